// Round 1
// baseline (97.034 us; speedup 1.0000x reference)
//
#include <hip/hip_runtime.h>
#include <hip/hip_bf16.h>

typedef unsigned short u16;
typedef unsigned int u32;
typedef __attribute__((ext_vector_type(8))) short short8;
typedef __attribute__((ext_vector_type(4))) float f32x4;

#define KDIM 2048
#define NP 1024

__device__ __forceinline__ float b2f(u16 u){
  union{u32 i; float f;} v; v.i = ((u32)u)<<16; return v.f;
}
__device__ __forceinline__ u16 f2b(float f){
  u32 x = __float_as_uint(f);
  return (u16)((x + 0x7fffu + ((x>>16)&1u)) >> 16);
}

__device__ __forceinline__ void gload16(const u16* g, u16* l){
  __builtin_amdgcn_global_load_lds((const __attribute__((address_space(1))) u32*)g,
                                   (__attribute__((address_space(3))) u32*)l, 16, 0, 0);
}

// ---- K0a: xs f32 -> bf16 (8192x2048), 8 elems/thread ----
__global__ __launch_bounds__(256) void k_cvt_xs(const float* __restrict__ xs, u16* __restrict__ A){
  int i = blockIdx.x*256 + threadIdx.x;            // octet index, 2,097,152 total
  const float4* s = (const float4*)xs;
  float4 a = s[2*i], c = s[2*i+1];
  u32 o0 = (u32)f2b(a.x) | ((u32)f2b(a.y)<<16);
  u32 o1 = (u32)f2b(a.z) | ((u32)f2b(a.w)<<16);
  u32 o2 = (u32)f2b(c.x) | ((u32)f2b(c.y)<<16);
  u32 o3 = (u32)f2b(c.z) | ((u32)f2b(c.w)<<16);
  *(uint4*)(A + 8*i) = make_uint4(o0,o1,o2,o3);
}

// ---- K0b: W f32 (1023x2048) -> bf16 padded (1024x2048), row 1023 = 0 ----
__global__ __launch_bounds__(256) void k_cvt_w(const float* __restrict__ W, u16* __restrict__ Wb){
  int i = blockIdx.x*256 + threadIdx.x;            // 262,144 total
  int e = i*8; int row = e >> 11;
  u32 o0=0,o1=0,o2=0,o3=0;
  if (row < 1023){
    const float4* s = (const float4*)(W + e);
    float4 a = s[0], c = s[1];
    o0 = (u32)f2b(a.x) | ((u32)f2b(a.y)<<16);
    o1 = (u32)f2b(a.z) | ((u32)f2b(a.w)<<16);
    o2 = (u32)f2b(c.x) | ((u32)f2b(c.y)<<16);
    o3 = (u32)f2b(c.z) | ((u32)f2b(c.w)<<16);
  }
  *(uint4*)(Wb + e) = make_uint4(o0,o1,o2,o3);
}

// ---- K0c: phi f32 (1024x24) -> phiT bf16 (32x1024), cols>=24 zero ----
__global__ __launch_bounds__(256) void k_phiT(const float* __restrict__ phi, u16* __restrict__ phiT){
  int i = blockIdx.x*256 + threadIdx.x;            // 0..32767
  int d = i >> 10, leaf = i & 1023;
  float v = (d < 24) ? phi[leaf*24 + d] : 0.f;
  phiT[i] = f2b(v);
}

// ---- K1: probs = sigmoid(A @ Wb^T + b), bf16 MFMA, 128x128 tile, BK=32 ----
__global__ __launch_bounds__(256) void k_gemm_sig(const u16* __restrict__ A, const u16* __restrict__ Wb,
                                                  const float* __restrict__ b, u16* __restrict__ probs){
  __shared__ __attribute__((aligned(16))) u16 At[4096];  // [128][32] bf16
  __shared__ __attribute__((aligned(16))) u16 Bt[4096];  // [128][32] bf16 (rows = output cols)
  const int t = threadIdx.x;
  const int l = t & 63;
  const int wid = t >> 6;
  const int wm = wid >> 1, wn = wid & 1;                 // 2x2 wave grid, 64x64 each
  const int rowB = (int)(blockIdx.x >> 3) * 128;
  const int colB = (int)(blockIdx.x & 7) * 128;

  const int li0 = t, li1 = t + 256;                      // staging linear idx (row=li>>2, kq=li&3)
  const u16* gA0 = A  + (size_t)(rowB + (li0>>2))*KDIM + (li0&3)*8;
  const u16* gA1 = A  + (size_t)(rowB + (li1>>2))*KDIM + (li1&3)*8;
  const u16* gB0 = Wb + (size_t)(colB + (li0>>2))*KDIM + (li0&3)*8;
  const u16* gB1 = Wb + (size_t)(colB + (li1>>2))*KDIM + (li1&3)*8;
  u16* lA0 = At + li0*8; u16* lA1 = At + li1*8;
  u16* lB0 = Bt + li0*8; u16* lB1 = Bt + li1*8;

  const int fo = (l&15)*32 + (l>>4)*8;                   // fragment base within 64-row panel
  const int ao = wm*64*32 + fo;
  const int bo = wn*64*32 + fo;

  f32x4 acc[4][4] = {};

  for (int kt=0; kt<64; ++kt){
    const int ko = kt*32;
    gload16(gA0+ko, lA0); gload16(gA1+ko, lA1);
    gload16(gB0+ko, lB0); gload16(gB1+ko, lB1);
    __syncthreads();                                     // drains vmcnt: tiles resident
    short8 af[4], bf[4];
    #pragma unroll
    for (int m=0;m<4;m++) af[m] = *(const short8*)(At + ao + m*512);
    #pragma unroll
    for (int n=0;n<4;n++) bf[n] = *(const short8*)(Bt + bo + n*512);
    #pragma unroll
    for (int m=0;m<4;m++){
      #pragma unroll
      for (int n=0;n<4;n++){
        acc[m][n] = __builtin_amdgcn_mfma_f32_16x16x32_bf16(af[m], bf[n], acc[m][n], 0,0,0);
      }
    }
    __syncthreads();                                     // protect LDS before next stage
  }

  #pragma unroll
  for (int n=0;n<4;n++){
    int col = colB + wn*64 + n*16 + (l&15);
    float bb = (col < 1023) ? b[col] : 0.f;
    #pragma unroll
    for (int m=0;m<4;m++){
      #pragma unroll
      for (int r=0;r<4;r++){
        int row = rowB + wm*64 + m*16 + (l>>4)*4 + r;    // measured C/D layout
        float x = acc[m][n][r] + bb;
        float p = 1.f / (1.f + __expf(-x));
        probs[(size_t)row*NP + col] = f2b(p);
      }
    }
  }
}

// ---- K2a: leaf path products. One wave per row; lane l owns leaves 16l..16l+15 ----
__global__ __launch_bounds__(256) void k_pp(const u16* __restrict__ probs, u16* __restrict__ pp){
  int gw = (blockIdx.x*256 + threadIdx.x) >> 6;          // row = global wave id (8192 waves)
  int l = threadIdx.x & 63;
  const u16* pr = probs + (size_t)gw*NP;
  float prefix = 1.f;
  #pragma unroll
  for (int k=0;k<6;k++){                                 // levels 0..5 shared by lane's 16 leaves
    int i = l >> (6-k);
    int bit = (l >> (5-k)) & 1;
    float p = b2f(pr[(1<<k)-1 + i]);
    prefix *= bit ? p : (1.f - p);
  }
  float p6 = b2f(pr[63 + l]);
  float p7[2], p8[4], p9[8];
  #pragma unroll
  for (int c=0;c<2;c++) p7[c] = b2f(pr[127 + 2*l + c]);
  #pragma unroll
  for (int c=0;c<4;c++) p8[c] = b2f(pr[255 + 4*l + c]);
  #pragma unroll
  for (int c=0;c<8;c++) p9[c] = b2f(pr[511 + 8*l + c]);
  u32 w[8];
  #pragma unroll
  for (int b6=0;b6<2;b6++){
    float s6 = prefix * (b6 ? p6 : 1.f - p6);
    #pragma unroll
    for (int b7=0;b7<2;b7++){
      float q7 = p7[b6];
      float s7 = s6 * (b7 ? q7 : 1.f - q7);
      #pragma unroll
      for (int b8=0;b8<2;b8++){
        float q8 = p8[2*b6+b7];
        float s8 = s7 * (b8 ? q8 : 1.f - q8);
        float q9 = p9[4*b6+2*b7+b8];
        w[4*b6+2*b7+b8] = (u32)f2b(s8 * (1.f - q9)) | ((u32)f2b(s8 * q9) << 16);
      }
    }
  }
  u32* d = (u32*)(pp + (size_t)gw*NP + l*16);
  *(uint4*)d     = make_uint4(w[0],w[1],w[2],w[3]);
  *(uint4*)(d+4) = make_uint4(w[4],w[5],w[6],w[7]);
}

// ---- K2b: out = pp @ phi via MFMA; M=8192, N=32(pad of 24), K=1024; 1 wave per 16 rows ----
__global__ __launch_bounds__(256) void k_out(const u16* __restrict__ pp, const u16* __restrict__ phiT,
                                             float* __restrict__ out){
  const int t = threadIdx.x;
  const int l = t & 63;
  const int wid = t >> 6;
  const int grp = blockIdx.x*4 + wid;                    // 0..511
  const int rbase = grp*16;
  f32x4 acc0 = {0.f,0.f,0.f,0.f}, acc1 = {0.f,0.f,0.f,0.f};
  const u16* ap  = pp   + (size_t)(rbase + (l&15))*NP + (l>>4)*8;
  const u16* bp0 = phiT + (size_t)(l&15)*NP + (l>>4)*8;
  const u16* bp1 = phiT + (size_t)(16+(l&15))*NP + (l>>4)*8;
  #pragma unroll 4
  for (int kk=0; kk<32; ++kk){
    short8 a  = *(const short8*)(ap  + kk*32);
    short8 b0 = *(const short8*)(bp0 + kk*32);
    short8 b1 = *(const short8*)(bp1 + kk*32);
    acc0 = __builtin_amdgcn_mfma_f32_16x16x32_bf16(a, b0, acc0, 0,0,0);
    acc1 = __builtin_amdgcn_mfma_f32_16x16x32_bf16(a, b1, acc1, 0,0,0);
  }
  #pragma unroll
  for (int r=0;r<4;r++){
    int row = rbase + (l>>4)*4 + r;
    out[row*24 + (l&15)] = acc0[r];
    if ((l&15) < 8) out[row*24 + 16 + (l&15)] = acc1[r];
  }
}

extern "C" void kernel_launch(void* const* d_in, const int* in_sizes, int n_in,
                              void* d_out, int out_size, void* d_ws, size_t ws_size,
                              hipStream_t stream){
  const float* xs  = (const float*)d_in[0];
  const float* W   = (const float*)d_in[1];
  const float* b   = (const float*)d_in[2];
  const float* phi = (const float*)d_in[3];
  float* out = (float*)d_out;
  char* ws = (char*)d_ws;
  // workspace layout (bytes):
  u16* A     = (u16*)(ws + 0);          // 8192*2048*2  = 33,554,432
  u16* Wb    = (u16*)(ws + 33554432);   // 1024*2048*2  =  4,194,304
  u16* probs = (u16*)(ws + 37748736);   // 8192*1024*2  = 16,777,216
  u16* phiT  = (u16*)(ws + 54525952);   // 32*1024*2    =     65,536
  u16* pp    = A;                       // alias: A is dead after K1; rewritten by K0a each call
  (void)in_sizes; (void)n_in; (void)out_size; (void)ws_size;

  k_cvt_xs <<<8192, 256, 0, stream>>>(xs, A);
  k_cvt_w  <<<1024, 256, 0, stream>>>(W, Wb);
  k_phiT   <<<128,  256, 0, stream>>>(phi, phiT);
  k_gemm_sig<<<512, 256, 0, stream>>>(A, Wb, b, probs);
  k_pp     <<<2048, 256, 0, stream>>>(probs, pp);
  k_out    <<<128,  256, 0, stream>>>(pp, phiT, out);
}

// Round 2
// 83.279 us; speedup vs baseline: 1.1652x; 1.1652x over previous
//
#include <hip/hip_runtime.h>
#include <hip/hip_bf16.h>

typedef unsigned short u16;
typedef unsigned int u32;
typedef __attribute__((ext_vector_type(8))) short short8;
typedef __attribute__((ext_vector_type(4))) float f32x4;

#define KDIM 2048
#define NP 1024

__device__ __forceinline__ float b2f(u16 u){
  union{u32 i; float f;} v; v.i = ((u32)u)<<16; return v.f;
}
__device__ __forceinline__ u16 f2b(float f){
  u32 x = __float_as_uint(f);
  return (u16)((x + 0x7fffu + ((x>>16)&1u)) >> 16);
}

__device__ __forceinline__ void gload16(const u16* g, u16* l){
  __builtin_amdgcn_global_load_lds((const __attribute__((address_space(1))) u32*)g,
                                   (__attribute__((address_space(3))) u32*)l, 16, 0, 0);
}

// ---- K0a: xs f32 -> bf16 (8192x2048) ----
__global__ __launch_bounds__(256) void k_cvt_xs(const float* __restrict__ xs, u16* __restrict__ A){
  int i = blockIdx.x*256 + threadIdx.x;
  const float4* s = (const float4*)xs;
  float4 a = s[2*i], c = s[2*i+1];
  u32 o0 = (u32)f2b(a.x) | ((u32)f2b(a.y)<<16);
  u32 o1 = (u32)f2b(a.z) | ((u32)f2b(a.w)<<16);
  u32 o2 = (u32)f2b(c.x) | ((u32)f2b(c.y)<<16);
  u32 o3 = (u32)f2b(c.z) | ((u32)f2b(c.w)<<16);
  *(uint4*)(A + 8*i) = make_uint4(o0,o1,o2,o3);
}

// ---- K0b: W f32 (1023x2048) -> bf16 padded (1024x2048) ----
__global__ __launch_bounds__(256) void k_cvt_w(const float* __restrict__ W, u16* __restrict__ Wb){
  int i = blockIdx.x*256 + threadIdx.x;
  int e = i*8; int row = e >> 11;
  u32 o0=0,o1=0,o2=0,o3=0;
  if (row < 1023){
    const float4* s = (const float4*)(W + e);
    float4 a = s[0], c = s[1];
    o0 = (u32)f2b(a.x) | ((u32)f2b(a.y)<<16);
    o1 = (u32)f2b(a.z) | ((u32)f2b(a.w)<<16);
    o2 = (u32)f2b(c.x) | ((u32)f2b(c.y)<<16);
    o3 = (u32)f2b(c.z) | ((u32)f2b(c.w)<<16);
  }
  *(uint4*)(Wb + e) = make_uint4(o0,o1,o2,o3);
}

// ---- K0c: phi f32 (1024x24) -> phiT bf16 (32x1024) ----
__global__ __launch_bounds__(256) void k_phiT(const float* __restrict__ phi, u16* __restrict__ phiT){
  int i = blockIdx.x*256 + threadIdx.x;
  int d = i >> 10, leaf = i & 1023;
  float v = (d < 24) ? phi[leaf*24 + d] : 0.f;
  phiT[i] = f2b(v);
}

// ---- K1: probs = sigmoid(A @ Wb^T + b) ----
// BM=256 BN=128 BK=64, 512 thr (8 waves, 4M x 2N, 64x64/wave), dbuf LDS 96KB,
// XOR-swizzled tiles (chunk ^= row&7), counted vmcnt(3), raw barriers, setprio.
__global__ __launch_bounds__(512, 2) void k_gemm_sig(const u16* __restrict__ A, const u16* __restrict__ Wb,
                                                     const float* __restrict__ b, u16* __restrict__ probs){
  extern __shared__ u16 smem[];
  const int t = threadIdx.x;
  const int l = t & 63;
  const int w = t >> 6;
  const int wm = w >> 1, wn = w & 1;
  const int bid = (int)blockIdx.x;
  const int wg = (bid & 7) * 32 + (bid >> 3);          // XCD-chunked, bijective (256%8==0)
  const int rowB = (wg >> 3) * 256;
  const int colB = (wg & 7) * 128;

  // staging: linear LDS dest (wave base + lane*16), inverse-swizzled global src
  const int locA0 = w*128 + l;                          // [0,1024): A chunk slot, instr 0
  const int locA1 = locA0 + 64;                         // instr 1
  const int rA0 = locA0 >> 3, cA0 = (locA0 & 7) ^ (rA0 & 7);
  const int rA1 = locA1 >> 3, cA1 = (locA1 & 7) ^ (rA1 & 7);
  const int locB = w*64 + l;                            // [0,512)
  const int rB = locB >> 3, cB = (locB & 7) ^ (rB & 7);
  const u16* gA0 = A  + (size_t)(rowB + rA0) * KDIM + cA0 * 8;
  const u16* gA1 = A  + (size_t)(rowB + rA1) * KDIM + cA1 * 8;
  const u16* gB  = Wb + (size_t)(colB + rB ) * KDIM + cB  * 8;
  const int dA0 = locA0 * 8, dA1 = locA1 * 8, dB = locB * 8;

  // fragment reads: slot s = (ks*4 + q) ^ (l&7); row&7 == l&7 for all frag rows
  const int r15 = l & 15, q = l >> 4, b7 = l & 7;
  const int xo0 = ((q    ) ^ b7) * 8;
  const int xo1 = ((4 + q) ^ b7) * 8;
  const int aRow = (wm*64 + r15) * 64;                  // u16 offset of frag row base
  const int bRow = (wn*64 + r15) * 64;

  f32x4 acc[4][4] = {};

#define AB(buf) (smem + (buf)*24576)
#define BB(buf) (smem + (buf)*24576 + 16384)
#define STAGE(p, buf, ko) do{ \
    gload16(gA0 + (size_t)(p)*128*KDIM + (ko), AB(buf) + (p)*8192 + dA0); \
    gload16(gA1 + (size_t)(p)*128*KDIM + (ko), AB(buf) + (p)*8192 + dA1); \
    gload16(gB  + (size_t)(p)*64 *KDIM + (ko), BB(buf) + (p)*4096 + dB ); \
  }while(0)

  STAGE(0, 0, 0); STAGE(1, 0, 0);                       // prologue: tile 0 fully issued

  for (int tk = 0; tk < 31; ++tk){
    const int cur = tk & 1, nxt = cur ^ 1;
    const int ko = (tk + 1) * 64;
    const u16* Ab = AB(cur); const u16* Bb = BB(cur);
    STAGE(0, nxt, ko);                                  // 3 loads of t+1 in flight
    asm volatile("s_waitcnt vmcnt(3)" ::: "memory");    // tile t fully landed
    __builtin_amdgcn_s_barrier();
    asm volatile("" ::: "memory");
    short8 af[4], bf[4];
    #pragma unroll
    for (int m=0;m<4;m++) af[m] = *(const short8*)(Ab + aRow + m*1024 + xo0);
    #pragma unroll
    for (int n=0;n<4;n++) bf[n] = *(const short8*)(Bb + bRow + n*1024 + xo0);
    __builtin_amdgcn_s_setprio(1);
    #pragma unroll
    for (int m=0;m<4;m++){
      #pragma unroll
      for (int n=0;n<4;n++) acc[m][n] = __builtin_amdgcn_mfma_f32_16x16x32_bf16(af[m], bf[n], acc[m][n], 0,0,0);
    }
    __builtin_amdgcn_s_setprio(0);
    STAGE(1, nxt, ko);
    #pragma unroll
    for (int m=0;m<4;m++) af[m] = *(const short8*)(Ab + aRow + m*1024 + xo1);
    #pragma unroll
    for (int n=0;n<4;n++) bf[n] = *(const short8*)(Bb + bRow + n*1024 + xo1);
    __builtin_amdgcn_s_setprio(1);
    #pragma unroll
    for (int m=0;m<4;m++){
      #pragma unroll
      for (int n=0;n<4;n++) acc[m][n] = __builtin_amdgcn_mfma_f32_16x16x32_bf16(af[m], bf[n], acc[m][n], 0,0,0);
    }
    __builtin_amdgcn_s_setprio(0);
    __builtin_amdgcn_s_barrier();                       // reads of cur consumed; nxt-writes safe
    asm volatile("" ::: "memory");
  }
  {                                                     // tail tile 31 (cur=1), no prefetch
    const u16* Ab = AB(1); const u16* Bb = BB(1);
    asm volatile("s_waitcnt vmcnt(0)" ::: "memory");
    __builtin_amdgcn_s_barrier();
    asm volatile("" ::: "memory");
    short8 af[4], bf[4];
    #pragma unroll
    for (int m=0;m<4;m++) af[m] = *(const short8*)(Ab + aRow + m*1024 + xo0);
    #pragma unroll
    for (int n=0;n<4;n++) bf[n] = *(const short8*)(Bb + bRow + n*1024 + xo0);
    #pragma unroll
    for (int m=0;m<4;m++){
      #pragma unroll
      for (int n=0;n<4;n++) acc[m][n] = __builtin_amdgcn_mfma_f32_16x16x32_bf16(af[m], bf[n], acc[m][n], 0,0,0);
    }
    #pragma unroll
    for (int m=0;m<4;m++) af[m] = *(const short8*)(Ab + aRow + m*1024 + xo1);
    #pragma unroll
    for (int n=0;n<4;n++) bf[n] = *(const short8*)(Bb + bRow + n*1024 + xo1);
    #pragma unroll
    for (int m=0;m<4;m++){
      #pragma unroll
      for (int n=0;n<4;n++) acc[m][n] = __builtin_amdgcn_mfma_f32_16x16x32_bf16(af[m], bf[n], acc[m][n], 0,0,0);
    }
  }
#undef STAGE
#undef AB
#undef BB

  #pragma unroll
  for (int n=0;n<4;n++){
    int col = colB + wn*64 + n*16 + r15;
    float bb = (col < 1023) ? b[col] : 0.f;
    #pragma unroll
    for (int m=0;m<4;m++){
      #pragma unroll
      for (int r=0;r<4;r++){
        int row = rowB + wm*64 + m*16 + q*4 + r;        // measured C/D layout
        float x = acc[m][n][r] + bb;
        float p = 1.f / (1.f + __expf(-x));
        probs[(size_t)row*NP + col] = f2b(p);
      }
    }
  }
}

// ---- K2a: leaf path products ----
__global__ __launch_bounds__(256) void k_pp(const u16* __restrict__ probs, u16* __restrict__ pp){
  int gw = (blockIdx.x*256 + threadIdx.x) >> 6;
  int l = threadIdx.x & 63;
  const u16* pr = probs + (size_t)gw*NP;
  float prefix = 1.f;
  #pragma unroll
  for (int k=0;k<6;k++){
    int i = l >> (6-k);
    int bit = (l >> (5-k)) & 1;
    float p = b2f(pr[(1<<k)-1 + i]);
    prefix *= bit ? p : (1.f - p);
  }
  float p6 = b2f(pr[63 + l]);
  float p7[2], p8[4], p9[8];
  #pragma unroll
  for (int c=0;c<2;c++) p7[c] = b2f(pr[127 + 2*l + c]);
  #pragma unroll
  for (int c=0;c<4;c++) p8[c] = b2f(pr[255 + 4*l + c]);
  #pragma unroll
  for (int c=0;c<8;c++) p9[c] = b2f(pr[511 + 8*l + c]);
  u32 wv[8];
  #pragma unroll
  for (int b6=0;b6<2;b6++){
    float s6 = prefix * (b6 ? p6 : 1.f - p6);
    #pragma unroll
    for (int b7=0;b7<2;b7++){
      float q7 = p7[b6];
      float s7 = s6 * (b7 ? q7 : 1.f - q7);
      #pragma unroll
      for (int b8=0;b8<2;b8++){
        float q8 = p8[2*b6+b7];
        float s8 = s7 * (b8 ? q8 : 1.f - q8);
        float q9 = p9[4*b6+2*b7+b8];
        wv[4*b6+2*b7+b8] = (u32)f2b(s8 * (1.f - q9)) | ((u32)f2b(s8 * q9) << 16);
      }
    }
  }
  u32* d = (u32*)(pp + (size_t)gw*NP + l*16);
  *(uint4*)d     = make_uint4(wv[0],wv[1],wv[2],wv[3]);
  *(uint4*)(d+4) = make_uint4(wv[4],wv[5],wv[6],wv[7]);
}

// ---- K2b: out = pp @ phi via MFMA ----
__global__ __launch_bounds__(256) void k_out(const u16* __restrict__ pp, const u16* __restrict__ phiT,
                                             float* __restrict__ out){
  const int t = threadIdx.x;
  const int l = t & 63;
  const int wid = t >> 6;
  const int grp = blockIdx.x*4 + wid;
  const int rbase = grp*16;
  f32x4 acc0 = {0.f,0.f,0.f,0.f}, acc1 = {0.f,0.f,0.f,0.f};
  const u16* ap  = pp   + (size_t)(rbase + (l&15))*NP + (l>>4)*8;
  const u16* bp0 = phiT + (size_t)(l&15)*NP + (l>>4)*8;
  const u16* bp1 = phiT + (size_t)(16+(l&15))*NP + (l>>4)*8;
  #pragma unroll 4
  for (int kk=0; kk<32; ++kk){
    short8 a  = *(const short8*)(ap  + kk*32);
    short8 b0 = *(const short8*)(bp0 + kk*32);
    short8 b1 = *(const short8*)(bp1 + kk*32);
    acc0 = __builtin_amdgcn_mfma_f32_16x16x32_bf16(a, b0, acc0, 0,0,0);
    acc1 = __builtin_amdgcn_mfma_f32_16x16x32_bf16(a, b1, acc1, 0,0,0);
  }
  #pragma unroll
  for (int r=0;r<4;r++){
    int row = rbase + (l>>4)*4 + r;
    out[row*24 + (l&15)] = acc0[r];
    if ((l&15) < 8) out[row*24 + 16 + (l&15)] = acc1[r];
  }
}

extern "C" void kernel_launch(void* const* d_in, const int* in_sizes, int n_in,
                              void* d_out, int out_size, void* d_ws, size_t ws_size,
                              hipStream_t stream){
  const float* xs  = (const float*)d_in[0];
  const float* W   = (const float*)d_in[1];
  const float* b   = (const float*)d_in[2];
  const float* phi = (const float*)d_in[3];
  float* out = (float*)d_out;
  char* ws = (char*)d_ws;
  u16* A     = (u16*)(ws + 0);          // 33,554,432 B
  u16* Wb    = (u16*)(ws + 33554432);   //  4,194,304 B
  u16* probs = (u16*)(ws + 37748736);   // 16,777,216 B
  u16* phiT  = (u16*)(ws + 54525952);   //     65,536 B
  u16* pp    = A;                       // alias: A dead after K1, rewritten each call
  (void)in_sizes; (void)n_in; (void)out_size; (void)ws_size;

  // 96KB dynamic LDS opt-in; first (uncaptured) call sets it, later calls idempotent
  hipFuncSetAttribute((const void*)k_gemm_sig, hipFuncAttributeMaxDynamicSharedMemorySize, 98304);

  k_cvt_xs <<<8192, 256, 0, stream>>>(xs, A);
  k_cvt_w  <<<1024, 256, 0, stream>>>(W, Wb);
  k_phiT   <<<128,  256, 0, stream>>>(phi, phiT);
  k_gemm_sig<<<256, 512, 98304, stream>>>(A, Wb, b, probs);
  k_pp     <<<2048, 256, 0, stream>>>(probs, pp);
  k_out    <<<128,  256, 0, stream>>>(pp, phiT, out);
}

// Round 3
// 79.396 us; speedup vs baseline: 1.2221x; 1.0489x over previous
//
#include <hip/hip_runtime.h>
#include <hip/hip_bf16.h>

typedef unsigned short u16;
typedef unsigned int u32;
typedef __attribute__((ext_vector_type(8))) short short8;
typedef __attribute__((ext_vector_type(4))) float f32x4;

#define KDIM 2048
#define NP 1024

__device__ __forceinline__ float b2f(u16 u){
  union{u32 i; float f;} v; v.i = ((u32)u)<<16; return v.f;
}
__device__ __forceinline__ u16 f2b(float f){
  u32 x = __float_as_uint(f);
  return (u16)((x + 0x7fffu + ((x>>16)&1u)) >> 16);
}

__device__ __forceinline__ void gload16(const u16* g, u16* l){
  __builtin_amdgcn_global_load_lds((const __attribute__((address_space(1))) u32*)g,
                                   (__attribute__((address_space(3))) u32*)l, 16, 0, 0);
}

#define BAR() do{ asm volatile("" ::: "memory"); __builtin_amdgcn_s_barrier(); asm volatile("" ::: "memory"); }while(0)

// ---- K0a: xs f32 -> bf16 (8192x2048) ----
__global__ __launch_bounds__(256) void k_cvt_xs(const float* __restrict__ xs, u16* __restrict__ A){
  int i = blockIdx.x*256 + threadIdx.x;
  const float4* s = (const float4*)xs;
  float4 a = s[2*i], c = s[2*i+1];
  u32 o0 = (u32)f2b(a.x) | ((u32)f2b(a.y)<<16);
  u32 o1 = (u32)f2b(a.z) | ((u32)f2b(a.w)<<16);
  u32 o2 = (u32)f2b(c.x) | ((u32)f2b(c.y)<<16);
  u32 o3 = (u32)f2b(c.z) | ((u32)f2b(c.w)<<16);
  *(uint4*)(A + 8*i) = make_uint4(o0,o1,o2,o3);
}

// ---- K0b: W -> bf16 padded (1024x2048) + phi -> phiT bf16 (32x1024), one launch ----
__global__ __launch_bounds__(256) void k_prep(const float* __restrict__ W, const float* __restrict__ phi,
                                              u16* __restrict__ Wb, u16* __restrict__ phiT){
  int bid = blockIdx.x;
  if (bid < 1024){
    int i = bid*256 + threadIdx.x;
    int e = i*8; int row = e >> 11;
    u32 o0=0,o1=0,o2=0,o3=0;
    if (row < 1023){
      const float4* s = (const float4*)(W + e);
      float4 a = s[0], c = s[1];
      o0 = (u32)f2b(a.x) | ((u32)f2b(a.y)<<16);
      o1 = (u32)f2b(a.z) | ((u32)f2b(a.w)<<16);
      o2 = (u32)f2b(c.x) | ((u32)f2b(c.y)<<16);
      o3 = (u32)f2b(c.z) | ((u32)f2b(c.w)<<16);
    }
    *(uint4*)(Wb + e) = make_uint4(o0,o1,o2,o3);
  } else {
    int i = (bid-1024)*256 + threadIdx.x;          // 0..32767
    int d = i >> 10, leaf = i & 1023;
    float v = (d < 24) ? phi[leaf*24 + d] : 0.f;
    phiT[i] = f2b(v);
  }
}

// ---- K1: probs = sigmoid(A @ Wb^T + b) ----
// BM=256 BN=128 BK=64, 512 thr (8 waves 4Mx2N, 64x64/wave), 3-buffer LDS 144KB,
// 2-tile-deep prefetch, 4 phases/tile {ds||stage, barrier, prio1, 8 MFMA, prio0, barrier},
// counted vmcnt(6) once per tile, XOR-swizzled tiles, XCD-chunked block swizzle.
__global__ __launch_bounds__(512, 2) void k_gemm_sig(const u16* __restrict__ A, const u16* __restrict__ Wb,
                                                     const float* __restrict__ b, u16* __restrict__ probs){
  extern __shared__ u16 smem[];                     // 3 * 24576 u16 = 147456 B
  const int t = threadIdx.x;
  const int l = t & 63;
  const int w = t >> 6;
  const int wm = w >> 1, wn = w & 1;
  const int bid = (int)blockIdx.x;
  const int wg = (bid & 7) * 32 + (bid >> 3);       // XCD-chunked, bijective (256%8==0)
  const int rowB = (wg >> 3) * 256;
  const int colB = (wg & 7) * 128;

  // staging: linear LDS dest, inverse-swizzled global source (rule 21)
  const int locA0 = w*128 + l;
  const int locA1 = locA0 + 64;
  const int rA0 = locA0 >> 3, cA0 = (locA0 & 7) ^ (rA0 & 7);
  const int rA1 = locA1 >> 3, cA1 = (locA1 & 7) ^ (rA1 & 7);
  const int locB = w*64 + l;
  const int rB = locB >> 3, cB = (locB & 7) ^ (rB & 7);
  const u16* gA0 = A  + (size_t)(rowB + rA0) * KDIM + cA0 * 8;
  const u16* gA1 = A  + (size_t)(rowB + rA1) * KDIM + cA1 * 8;
  const u16* gB  = Wb + (size_t)(colB + rB ) * KDIM + cB  * 8;
  const int dA0 = locA0 * 8, dA1 = locA1 * 8, dB = locB * 8;

  // fragment read offsets: slot s = (ks*4+q) ^ (l&7)
  const int r15 = l & 15, q = l >> 4, b7 = l & 7;
  const int xo0 = ((q    ) ^ b7) * 8;
  const int xo1 = ((4 + q) ^ b7) * 8;
  const int aRow = (wm*64 + r15) * 64;
  const int bRow = (wn*64 + r15) * 64;

  f32x4 acc[4][4] = {};

#define SA(buf, p, ko) do{ \
    gload16(gA0 + (size_t)(p)*128*KDIM + (ko), (buf) + (p)*8192 + dA0); \
    gload16(gA1 + (size_t)(p)*128*KDIM + (ko), (buf) + (p)*8192 + dA1); }while(0)
#define SB(buf, p, ko) \
    gload16(gB + (size_t)(p)*64*KDIM + (ko), (buf) + 16384 + (p)*4096 + dB)

  u16 *bc = smem, *bn = smem + 24576, *bs = smem + 49152;

  // prologue: tiles 0 and 1 fully issued (12 loads)
  SA(bc,0,0); SA(bc,1,0); SB(bc,0,0); SB(bc,1,0);
  SA(bn,0,64); SA(bn,1,64); SB(bn,0,64); SB(bn,1,64);
  asm volatile("s_waitcnt vmcnt(6)" ::: "memory");  // tile 0 landed (this wave)
  BAR();                                            // ... for all waves

  for (int tk = 0; tk < 32; ++tk){
    const int ko2 = (tk + 2) * 64;
    const bool st = (tk < 30);
    short8 af0, af1, af2, af3, bf0, bf1, bf2, bf3;
    // ---- phase 0: ks0 m-half0 + all bf(ks0); stage U0(t+2) ----
    af0 = *(const short8*)(bc + aRow + 0*1024 + xo0);
    af1 = *(const short8*)(bc + aRow + 1*1024 + xo0);
    bf0 = *(const short8*)(bc + 16384 + bRow + 0*1024 + xo0);
    bf1 = *(const short8*)(bc + 16384 + bRow + 1*1024 + xo0);
    bf2 = *(const short8*)(bc + 16384 + bRow + 2*1024 + xo0);
    bf3 = *(const short8*)(bc + 16384 + bRow + 3*1024 + xo0);
    if (st) SA(bs, 0, ko2);
    BAR();
    __builtin_amdgcn_s_setprio(1);
    acc[0][0] = __builtin_amdgcn_mfma_f32_16x16x32_bf16(af0, bf0, acc[0][0], 0,0,0);
    acc[0][1] = __builtin_amdgcn_mfma_f32_16x16x32_bf16(af0, bf1, acc[0][1], 0,0,0);
    acc[0][2] = __builtin_amdgcn_mfma_f32_16x16x32_bf16(af0, bf2, acc[0][2], 0,0,0);
    acc[0][3] = __builtin_amdgcn_mfma_f32_16x16x32_bf16(af0, bf3, acc[0][3], 0,0,0);
    acc[1][0] = __builtin_amdgcn_mfma_f32_16x16x32_bf16(af1, bf0, acc[1][0], 0,0,0);
    acc[1][1] = __builtin_amdgcn_mfma_f32_16x16x32_bf16(af1, bf1, acc[1][1], 0,0,0);
    acc[1][2] = __builtin_amdgcn_mfma_f32_16x16x32_bf16(af1, bf2, acc[1][2], 0,0,0);
    acc[1][3] = __builtin_amdgcn_mfma_f32_16x16x32_bf16(af1, bf3, acc[1][3], 0,0,0);
    __builtin_amdgcn_s_setprio(0);
    BAR();
    // ---- phase 1: ks0 m-half1; stage U1(t+2) ----
    af2 = *(const short8*)(bc + aRow + 2*1024 + xo0);
    af3 = *(const short8*)(bc + aRow + 3*1024 + xo0);
    if (st) SA(bs, 1, ko2);
    BAR();
    __builtin_amdgcn_s_setprio(1);
    acc[2][0] = __builtin_amdgcn_mfma_f32_16x16x32_bf16(af2, bf0, acc[2][0], 0,0,0);
    acc[2][1] = __builtin_amdgcn_mfma_f32_16x16x32_bf16(af2, bf1, acc[2][1], 0,0,0);
    acc[2][2] = __builtin_amdgcn_mfma_f32_16x16x32_bf16(af2, bf2, acc[2][2], 0,0,0);
    acc[2][3] = __builtin_amdgcn_mfma_f32_16x16x32_bf16(af2, bf3, acc[2][3], 0,0,0);
    acc[3][0] = __builtin_amdgcn_mfma_f32_16x16x32_bf16(af3, bf0, acc[3][0], 0,0,0);
    acc[3][1] = __builtin_amdgcn_mfma_f32_16x16x32_bf16(af3, bf1, acc[3][1], 0,0,0);
    acc[3][2] = __builtin_amdgcn_mfma_f32_16x16x32_bf16(af3, bf2, acc[3][2], 0,0,0);
    acc[3][3] = __builtin_amdgcn_mfma_f32_16x16x32_bf16(af3, bf3, acc[3][3], 0,0,0);
    __builtin_amdgcn_s_setprio(0);
    BAR();
    // ---- phase 2: ks1 m-half0 + all bf(ks1); stage U2(t+2) ----
    af0 = *(const short8*)(bc + aRow + 0*1024 + xo1);
    af1 = *(const short8*)(bc + aRow + 1*1024 + xo1);
    bf0 = *(const short8*)(bc + 16384 + bRow + 0*1024 + xo1);
    bf1 = *(const short8*)(bc + 16384 + bRow + 1*1024 + xo1);
    bf2 = *(const short8*)(bc + 16384 + bRow + 2*1024 + xo1);
    bf3 = *(const short8*)(bc + 16384 + bRow + 3*1024 + xo1);
    if (st){ SB(bs, 0, ko2); SB(bs, 1, ko2); }
    BAR();
    __builtin_amdgcn_s_setprio(1);
    acc[0][0] = __builtin_amdgcn_mfma_f32_16x16x32_bf16(af0, bf0, acc[0][0], 0,0,0);
    acc[0][1] = __builtin_amdgcn_mfma_f32_16x16x32_bf16(af0, bf1, acc[0][1], 0,0,0);
    acc[0][2] = __builtin_amdgcn_mfma_f32_16x16x32_bf16(af0, bf2, acc[0][2], 0,0,0);
    acc[0][3] = __builtin_amdgcn_mfma_f32_16x16x32_bf16(af0, bf3, acc[0][3], 0,0,0);
    acc[1][0] = __builtin_amdgcn_mfma_f32_16x16x32_bf16(af1, bf0, acc[1][0], 0,0,0);
    acc[1][1] = __builtin_amdgcn_mfma_f32_16x16x32_bf16(af1, bf1, acc[1][1], 0,0,0);
    acc[1][2] = __builtin_amdgcn_mfma_f32_16x16x32_bf16(af1, bf2, acc[1][2], 0,0,0);
    acc[1][3] = __builtin_amdgcn_mfma_f32_16x16x32_bf16(af1, bf3, acc[1][3], 0,0,0);
    __builtin_amdgcn_s_setprio(0);
    BAR();
    // ---- phase 3: ks1 m-half1; tile-boundary vmcnt ----
    af2 = *(const short8*)(bc + aRow + 2*1024 + xo1);
    af3 = *(const short8*)(bc + aRow + 3*1024 + xo1);
    BAR();
    __builtin_amdgcn_s_setprio(1);
    acc[2][0] = __builtin_amdgcn_mfma_f32_16x16x32_bf16(af2, bf0, acc[2][0], 0,0,0);
    acc[2][1] = __builtin_amdgcn_mfma_f32_16x16x32_bf16(af2, bf1, acc[2][1], 0,0,0);
    acc[2][2] = __builtin_amdgcn_mfma_f32_16x16x32_bf16(af2, bf2, acc[2][2], 0,0,0);
    acc[2][3] = __builtin_amdgcn_mfma_f32_16x16x32_bf16(af2, bf3, acc[2][3], 0,0,0);
    acc[3][0] = __builtin_amdgcn_mfma_f32_16x16x32_bf16(af3, bf0, acc[3][0], 0,0,0);
    acc[3][1] = __builtin_amdgcn_mfma_f32_16x16x32_bf16(af3, bf1, acc[3][1], 0,0,0);
    acc[3][2] = __builtin_amdgcn_mfma_f32_16x16x32_bf16(af3, bf2, acc[3][2], 0,0,0);
    acc[3][3] = __builtin_amdgcn_mfma_f32_16x16x32_bf16(af3, bf3, acc[3][3], 0,0,0);
    __builtin_amdgcn_s_setprio(0);
    if (tk < 30)       asm volatile("s_waitcnt vmcnt(6)" ::: "memory");  // tile t+1 landed
    else if (tk == 30) asm volatile("s_waitcnt vmcnt(0)" ::: "memory");
    BAR();
    u16* tmp = bc; bc = bn; bn = bs; bs = tmp;      // rotate 3 buffers
  }
#undef SA
#undef SB

  #pragma unroll
  for (int n=0;n<4;n++){
    int col = colB + wn*64 + n*16 + r15;
    float bb = (col < 1023) ? b[col] : 0.f;
    #pragma unroll
    for (int m=0;m<4;m++){
      #pragma unroll
      for (int r=0;r<4;r++){
        int row = rowB + wm*64 + m*16 + q*4 + r;    // measured C/D layout
        float x = acc[m][n][r] + bb;
        float p = 1.f / (1.f + __expf(-x));
        probs[(size_t)row*NP + col] = f2b(p);
      }
    }
  }
}

// ---- K2: fused leaf products + pp@phi. 128 thr (2 waves), wave-private 16 rows,
// pp staged in XOR-swizzled LDS, MFMA epilogue straight from LDS. ----
__global__ __launch_bounds__(128) void k_ppout(const u16* __restrict__ probs, const u16* __restrict__ phiT,
                                               float* __restrict__ out){
  extern __shared__ u16 ppL[];                      // 2 waves * 16 rows * 1024 = 64KB
  const int t = threadIdx.x;
  const int l = t & 63;
  const int w = t >> 6;
  u16* pl = ppL + w*16384;
  const int row0 = blockIdx.x*32 + w*16;

  for (int r=0; r<16; ++r){
    const u16* pr = probs + (size_t)(row0 + r)*NP;
    float prefix = 1.f;
    #pragma unroll
    for (int k=0;k<6;k++){
      int i = l >> (6-k);
      int bit = (l >> (5-k)) & 1;
      float p = b2f(pr[(1<<k)-1 + i]);
      prefix *= bit ? p : (1.f - p);
    }
    float p6 = b2f(pr[63 + l]);
    float p7[2], p8[4], p9[8];
    #pragma unroll
    for (int c=0;c<2;c++) p7[c] = b2f(pr[127 + 2*l + c]);
    #pragma unroll
    for (int c=0;c<4;c++) p8[c] = b2f(pr[255 + 4*l + c]);
    #pragma unroll
    for (int c=0;c<8;c++) p9[c] = b2f(pr[511 + 8*l + c]);
    u32 wv[8];
    #pragma unroll
    for (int b6=0;b6<2;b6++){
      float s6 = prefix * (b6 ? p6 : 1.f - p6);
      #pragma unroll
      for (int b7=0;b7<2;b7++){
        float q7 = p7[b6];
        float s7 = s6 * (b7 ? q7 : 1.f - q7);
        #pragma unroll
        for (int b8=0;b8<2;b8++){
          float q8 = p8[2*b6+b7];
          float s8 = s7 * (b8 ? q8 : 1.f - q8);
          float q9 = p9[4*b6+2*b7+b8];
          wv[4*b6+2*b7+b8] = (u32)f2b(s8 * (1.f - q9)) | ((u32)f2b(s8 * q9) << 16);
        }
      }
    }
    // swizzled store: chunk c of row r -> slot c ^ (r&7)
    int s0 = ((2*l  ) ^ (r&7)) * 8;
    int s1 = ((2*l+1) ^ (r&7)) * 8;
    *(uint4*)(pl + r*1024 + s0) = make_uint4(wv[0],wv[1],wv[2],wv[3]);
    *(uint4*)(pl + r*1024 + s1) = make_uint4(wv[4],wv[5],wv[6],wv[7]);
  }

  // MFMA: out[16x24] = pp[16x1024] @ phiT^T (N padded to 32)
  const int r15 = l & 15, q = l >> 4;
  f32x4 acc0 = {0.f,0.f,0.f,0.f}, acc1 = {0.f,0.f,0.f,0.f};
  const u16* bp0 = phiT + (size_t)r15*NP + q*8;
  const u16* bp1 = phiT + (size_t)(16+r15)*NP + q*8;
  #pragma unroll 4
  for (int kk=0; kk<32; ++kk){
    int slot = ((q + kk*4) ^ (r15 & 7)) * 8;
    short8 a  = *(const short8*)(pl + r15*1024 + slot);
    short8 b0 = *(const short8*)(bp0 + kk*32);
    short8 b1 = *(const short8*)(bp1 + kk*32);
    acc0 = __builtin_amdgcn_mfma_f32_16x16x32_bf16(a, b0, acc0, 0,0,0);
    acc1 = __builtin_amdgcn_mfma_f32_16x16x32_bf16(a, b1, acc1, 0,0,0);
  }
  #pragma unroll
  for (int r=0;r<4;r++){
    int row = row0 + q*4 + r;
    out[row*24 + r15] = acc0[r];
    if (r15 < 8) out[row*24 + 16 + r15] = acc1[r];
  }
}

extern "C" void kernel_launch(void* const* d_in, const int* in_sizes, int n_in,
                              void* d_out, int out_size, void* d_ws, size_t ws_size,
                              hipStream_t stream){
  const float* xs  = (const float*)d_in[0];
  const float* W   = (const float*)d_in[1];
  const float* b   = (const float*)d_in[2];
  const float* phi = (const float*)d_in[3];
  float* out = (float*)d_out;
  char* ws = (char*)d_ws;
  u16* A     = (u16*)(ws + 0);          // 33,554,432 B
  u16* Wb    = (u16*)(ws + 33554432);   //  4,194,304 B
  u16* probs = (u16*)(ws + 37748736);   // 16,777,216 B
  u16* phiT  = (u16*)(ws + 54525952);   //     65,536 B
  (void)in_sizes; (void)n_in; (void)out_size; (void)ws_size;

  hipFuncSetAttribute((const void*)k_gemm_sig, hipFuncAttributeMaxDynamicSharedMemorySize, 147456);
  hipFuncSetAttribute((const void*)k_ppout,    hipFuncAttributeMaxDynamicSharedMemorySize, 65536);

  k_cvt_xs <<<8192, 256, 0, stream>>>(xs, A);
  k_prep   <<<1152, 256, 0, stream>>>(W, phi, Wb, phiT);
  k_gemm_sig<<<256, 512, 147456, stream>>>(A, Wb, b, probs);
  k_ppout  <<<256, 128, 65536, stream>>>(probs, phiT, out);
}